// Round 1
// 560.915 us; speedup vs baseline: 1.1445x; 1.1445x over previous
//
#include <hip/hip_runtime.h>

// Problem constants (fixed by the reference file).
#define BN 2
#define NN 50000
#define EE 500000
#define DD 128
#define OO 128

typedef float f2v __attribute__((ext_vector_type(2)));
typedef __attribute__((ext_vector_type(8))) __bf16 bf16x8;
typedef __attribute__((ext_vector_type(4))) float f32x4;

// ---------------------------------------------------------------------------
// Wf = W_msg @ W_upd (384x128) computed in fp32, then split into bf16 hi/lo
// and written directly in per-lane MFMA B-fragment layout:
//   frag index = ((kstep*8 + coltile)*64 + lane)*8 + e
//   lane = (k%32/8)*16 + (o%16),  e = k%8,  kstep = k/32, coltile = o/16
// bmu = b_msg @ W_upd stays fp32 (epilogue-only).
// ---------------------------------------------------------------------------
__global__ __launch_bounds__(128) void wfuse_k(
    const float* __restrict__ Wm, const float* __restrict__ Wu,
    const float* __restrict__ bm, unsigned short* __restrict__ Wph,
    unsigned short* __restrict__ Wpl, float* __restrict__ bmu) {
    const int o = threadIdx.x;
    const int k = blockIdx.x;
    float s = 0.0f;
    if (k < 3 * DD) {
#pragma unroll 4
        for (int j = 0; j < OO; ++j) s += Wm[k * OO + j] * Wu[j * OO + o];
        // exact split: s = hi + lo + O(2^-14 * s)
        const unsigned int u = __float_as_uint(s);
        const unsigned short hi = (unsigned short)(u >> 16);
        const float r = s - __uint_as_float(u & 0xffff0000u);
        const unsigned short lo = (unsigned short)(__float_as_uint(r) >> 16);
        const int kstep = k >> 5;
        const int kr = k & 31;
        const int lane = (kr >> 3) * 16 + (o & 15);
        const int ct = o >> 4;
        const int idx = (((kstep * 8) + ct) * 64 + lane) * 8 + (kr & 7);
        Wph[idx] = hi;
        Wpl[idx] = lo;
    } else {
#pragma unroll 4
        for (int j = 0; j < OO; ++j) s += bm[j] * Wu[j * OO + o];
        bmu[o] = s;
    }
}

// ---------------------------------------------------------------------------
// CSR build: histogram -> 3-phase parallel scan -> fill (packed int2).
// ---------------------------------------------------------------------------
__global__ __launch_bounds__(256) void hist_k(const int* __restrict__ ei,
                                              int* __restrict__ hist) {
    int gid = blockIdx.x * 256 + threadIdx.x;
    if (gid >= EE) return;
    atomicAdd(&hist[ei[EE + gid]], 1);
}

__global__ __launch_bounds__(256) void scan1_k(const int* __restrict__ hist,
                                               int* __restrict__ bsum) {
    int i = blockIdx.x * 256 + threadIdx.x;
    int v = (i < NN) ? hist[i] : 0;
#pragma unroll
    for (int off = 32; off > 0; off >>= 1) v += __shfl_down(v, off);
    __shared__ int ws[4];
    if ((threadIdx.x & 63) == 0) ws[threadIdx.x >> 6] = v;
    __syncthreads();
    if (threadIdx.x == 0) bsum[blockIdx.x] = ws[0] + ws[1] + ws[2] + ws[3];
}

__global__ __launch_bounds__(256) void scan2_k(const int* __restrict__ bsum,
                                               int* __restrict__ ebsum,
                                               int* __restrict__ offsets,
                                               int nblk) {
    __shared__ int s[256];
    const int t = threadIdx.x;
    int v = (t < nblk) ? bsum[t] : 0;
    s[t] = v;
    __syncthreads();
    for (int off = 1; off < 256; off <<= 1) {
        int u = (t >= off) ? s[t - off] : 0;
        __syncthreads();
        s[t] += u;
        __syncthreads();
    }
    ebsum[t] = s[t] - v;
    if (t == 0) offsets[NN] = EE;
}

__global__ __launch_bounds__(256) void scan3_k(const int* __restrict__ hist,
                                               const int* __restrict__ ebsum,
                                               int* __restrict__ offsets,
                                               int* __restrict__ cursor) {
    __shared__ int s[256];
    const int t = threadIdx.x;
    const int i = blockIdx.x * 256 + t;
    int v = (i < NN) ? hist[i] : 0;
    s[t] = v;
    __syncthreads();
    for (int off = 1; off < 256; off <<= 1) {
        int u = (t >= off) ? s[t - off] : 0;
        __syncthreads();
        s[t] += u;
        __syncthreads();
    }
    int ex = s[t] - v + ebsum[blockIdx.x];
    if (i < NN) { offsets[i] = ex; cursor[i] = ex; }
}

__global__ __launch_bounds__(256) void fill_k(const int* __restrict__ ei,
                                              int* __restrict__ cursor,
                                              int2* __restrict__ ep) {
    int gid = blockIdx.x * 256 + threadIdx.x;
    if (gid >= EE) return;
    int dst = ei[EE + gid];
    int pos = atomicAdd(&cursor[dst], 1);
    ep[pos] = make_int2(gid, ei[gid]);
}

// ---------------------------------------------------------------------------
// Gather-aggregate: one wave per dst node, lane owns float2. Unroll x4.
// ea streamed with nontemporal loads (protect x's LLC residency).
// ---------------------------------------------------------------------------
__global__ __launch_bounds__(256) void agg_k(
    const float* __restrict__ x,      // (BN, NN, DD)
    const float* __restrict__ ea,     // (EE, DD)
    const int* __restrict__ offsets,  // (NN+1)
    const int2* __restrict__ ep,      // (EE) {edge, src}
    float* __restrict__ S,            // (BN, NN, DD)
    float* __restrict__ T,            // (NN, DD)
    float* __restrict__ cnt)          // (NN)
{
    const int n = (blockIdx.x * 256 + threadIdx.x) >> 6;
    if (n >= NN) return;
    const int lane = threadIdx.x & 63;

    const int beg = offsets[n];
    const int end = offsets[n + 1];

    f2v tA = {0, 0}, s0A = {0, 0}, s1A = {0, 0};

    int j = beg;
    for (; j + 3 < end; j += 4) {
        int2 p0 = ep[j], p1 = ep[j + 1], p2 = ep[j + 2], p3 = ep[j + 3];
        f2v v0 = __builtin_nontemporal_load((const f2v*)(ea + (size_t)p0.x * DD) + lane);
        f2v v1 = __builtin_nontemporal_load((const f2v*)(ea + (size_t)p1.x * DD) + lane);
        f2v v2 = __builtin_nontemporal_load((const f2v*)(ea + (size_t)p2.x * DD) + lane);
        f2v v3 = __builtin_nontemporal_load((const f2v*)(ea + (size_t)p3.x * DD) + lane);
        f2v a0 = ((const f2v*)(x + (size_t)p0.y * DD))[lane];
        f2v a1 = ((const f2v*)(x + (size_t)p1.y * DD))[lane];
        f2v a2 = ((const f2v*)(x + (size_t)p2.y * DD))[lane];
        f2v a3 = ((const f2v*)(x + (size_t)p3.y * DD))[lane];
        f2v b0 = ((const f2v*)(x + ((size_t)NN + p0.y) * DD))[lane];
        f2v b1 = ((const f2v*)(x + ((size_t)NN + p1.y) * DD))[lane];
        f2v b2 = ((const f2v*)(x + ((size_t)NN + p2.y) * DD))[lane];
        f2v b3 = ((const f2v*)(x + ((size_t)NN + p3.y) * DD))[lane];
        tA  += v0 + v1 + v2 + v3;
        s0A += a0 + a1 + a2 + a3;
        s1A += b0 + b1 + b2 + b3;
    }
    for (; j < end; ++j) {
        int2 p = ep[j];
        f2v v = __builtin_nontemporal_load((const f2v*)(ea + (size_t)p.x * DD) + lane);
        f2v a = ((const f2v*)(x + (size_t)p.y * DD))[lane];
        f2v b = ((const f2v*)(x + ((size_t)NN + p.y) * DD))[lane];
        tA += v; s0A += a; s1A += b;
    }

    ((f2v*)(T + (size_t)n * DD))[lane] = tA;
    ((f2v*)(S + (size_t)n * DD))[lane] = s0A;
    ((f2v*)(S + ((size_t)NN + n) * DD))[lane] = s1A;
    if (lane == 0) cnt[n] = (float)(end - beg);
}

// ---------------------------------------------------------------------------
// MFMA GEMM: out = diag(1/max(c,1)) * (A @ Wf) + (c>0)*bmu + bu
// A = [S | c*x | T] (100000 x 384), built on the fly per 128-K chunk
// (chunk == segment). Split-bf16 3-term MFMA (hi*hi + lo*hi + hi*lo)
// reproduces fp32 products to ~2^-14 rel — dropped lo*lo only.
//   block: 64 rows x 128 cols, 4 waves (wave = 32 cols)
//   LDS: A-tile hi/lo bf16 [64][128], XOR-swizzled (byte ^= (row&7)<<4)
//        -> conflict-free ds_write_b128 / ds_read_b128 (verified bank math)
//   W: pre-packed per-lane fragments (hi/lo), coalesced 16B global loads,
//      L2-resident (192 KB total).
// mfma_f32_16x16x32_bf16; C/D layout col=lane&15, row=(lane>>4)*4+reg (m89).
// ---------------------------------------------------------------------------
__global__ __launch_bounds__(256, 4) void gemm_k(
    const float* __restrict__ S,
    const float* __restrict__ T,
    const float* __restrict__ cnt,
    const float* __restrict__ x,
    const unsigned short* __restrict__ Wph,  // packed bf16-hi frags
    const unsigned short* __restrict__ Wpl,  // packed bf16-lo frags
    const float* __restrict__ bmu,           // (128,)
    const float* __restrict__ bu,            // (128,)
    float* __restrict__ out)                 // (BN*NN, 128)
{
    __shared__ unsigned short Ahi[64 * 128];  // 16 KB
    __shared__ unsigned short Alo[64 * 128];  // 16 KB

    const int tid = threadIdx.x;
    const int R0 = blockIdx.x * 64;
    const int wv = tid >> 6;    // wave id 0..3 -> cols wv*32..+32
    const int l = tid & 63;

    // staging map: 4 threads per row, 32 consecutive k each
    const int srow = tid >> 2;
    const int skq = (tid & 3) * 32;
    const int Rs = R0 + srow;
    const bool sv = Rs < BN * NN;
    const int ns = sv ? (Rs < NN ? Rs : Rs - NN) : 0;
    const int swz = (srow & 7) << 4;
    const float cs = sv ? cnt[ns] : 0.0f;

    f32x4 acc[4][2];
#pragma unroll
    for (int i = 0; i < 4; ++i) {
        acc[i][0] = (f32x4){0.0f, 0.0f, 0.0f, 0.0f};
        acc[i][1] = (f32x4){0.0f, 0.0f, 0.0f, 0.0f};
    }

    for (int seg = 0; seg < 3; ++seg) {
        // ---- stage A chunk (64 rows x 128 k) as bf16 hi/lo into LDS ----
        const float4* p = nullptr;
        if (sv) {
            p = (seg == 0) ? (const float4*)(S + (size_t)Rs * DD + skq)
              : (seg == 1) ? (const float4*)(x + (size_t)Rs * DD + skq)
                           : (const float4*)(T + (size_t)ns * DD + skq);
        }
#pragma unroll
        for (int j = 0; j < 4; ++j) {
            float4 u0 = {0, 0, 0, 0}, u1 = {0, 0, 0, 0};
            if (sv) {
                u0 = p[2 * j];
                u1 = p[2 * j + 1];
                if (seg == 1) {
                    u0.x *= cs; u0.y *= cs; u0.z *= cs; u0.w *= cs;
                    u1.x *= cs; u1.y *= cs; u1.z *= cs; u1.w *= cs;
                }
            }
            const float vv[8] = {u0.x, u0.y, u0.z, u0.w, u1.x, u1.y, u1.z, u1.w};
            unsigned int hw[4], lw[4];
#pragma unroll
            for (int i = 0; i < 4; ++i) {
                const unsigned int b0 = __float_as_uint(vv[2 * i]);
                const unsigned int b1 = __float_as_uint(vv[2 * i + 1]);
                const float r0 = vv[2 * i]     - __uint_as_float(b0 & 0xffff0000u);
                const float r1 = vv[2 * i + 1] - __uint_as_float(b1 & 0xffff0000u);
                hw[i] = (b0 >> 16) | (b1 & 0xffff0000u);
                lw[i] = (__float_as_uint(r0) >> 16) | (__float_as_uint(r1) & 0xffff0000u);
            }
            const int byt = srow * 256 + (((skq + j * 8) * 2) ^ swz);
            *(int4*)((char*)Ahi + byt) = make_int4(hw[0], hw[1], hw[2], hw[3]);
            *(int4*)((char*)Alo + byt) = make_int4(lw[0], lw[1], lw[2], lw[3]);
        }
        __syncthreads();

        // ---- compute: 4 MFMA k-steps of 32 over this chunk ----
#pragma unroll
        for (int ks = 0; ks < 4; ++ks) {
            bf16x8 ah[4], al[4];
#pragma unroll
            for (int rt = 0; rt < 4; ++rt) {
                const int row = rt * 16 + (l & 15);
                const int rb = row * 256 +
                               ((ks * 64 + (l >> 4) * 16) ^ ((row & 7) << 4));
                ah[rt] = *(const bf16x8*)((const char*)Ahi + rb);
                al[rt] = *(const bf16x8*)((const char*)Alo + rb);
            }
            const int kg = seg * 4 + ks;
#pragma unroll
            for (int ct = 0; ct < 2; ++ct) {
                const size_t fi =
                    (size_t)(((kg * 8) + (wv * 2 + ct)) * 64 + l) * 8;
                const bf16x8 wh = *(const bf16x8*)(Wph + fi);
                const bf16x8 wl = *(const bf16x8*)(Wpl + fi);
#pragma unroll
                for (int rt = 0; rt < 4; ++rt) {
                    acc[rt][ct] = __builtin_amdgcn_mfma_f32_16x16x32_bf16(
                        ah[rt], wh, acc[rt][ct], 0, 0, 0);
                    acc[rt][ct] = __builtin_amdgcn_mfma_f32_16x16x32_bf16(
                        al[rt], wh, acc[rt][ct], 0, 0, 0);
                    acc[rt][ct] = __builtin_amdgcn_mfma_f32_16x16x32_bf16(
                        ah[rt], wl, acc[rt][ct], 0, 0, 0);
                }
            }
        }
        __syncthreads();
    }

    // ---- epilogue ----
    const int col0 = wv * 32 + (l & 15);
    const float bm0 = bmu[col0], bm1 = bmu[col0 + 16];
    const float bu0 = bu[col0], bu1 = bu[col0 + 16];
    const int rbase = (l >> 4) * 4;
#pragma unroll
    for (int rt = 0; rt < 4; ++rt) {
#pragma unroll
        for (int r = 0; r < 4; ++r) {
            const int Rr = R0 + rt * 16 + rbase + r;
            if (Rr < BN * NN) {
                const int nr = (Rr < NN) ? Rr : Rr - NN;
                const float c = cnt[nr];
                const float inv = 1.0f / fmaxf(c, 1.0f);
                const float g = (c > 0.0f) ? 1.0f : 0.0f;
                __builtin_nontemporal_store(
                    acc[rt][0][r] * inv + g * bm0 + bu0,
                    out + (size_t)Rr * OO + col0);
                __builtin_nontemporal_store(
                    acc[rt][1][r] * inv + g * bm1 + bu1,
                    out + (size_t)Rr * OO + col0 + 16);
            }
        }
    }
}

extern "C" void kernel_launch(void* const* d_in, const int* in_sizes, int n_in,
                              void* d_out, int out_size, void* d_ws, size_t ws_size,
                              hipStream_t stream) {
    const float* x  = (const float*)d_in[0];
    const int*   ei = (const int*)d_in[1];
    const float* ea = (const float*)d_in[2];
    const float* Wm = (const float*)d_in[3];
    const float* bm = (const float*)d_in[4];
    const float* Wu = (const float*)d_in[5];
    const float* bu = (const float*)d_in[6];
    float* out = (float*)d_out;

    // workspace layout
    float* S   = (float*)d_ws;                        // 12,800,000 f
    float* T   = S + (size_t)BN * NN * DD;            //  6,400,000 f
    float* cnt = T + (size_t)NN * DD;                 //     50,000 f
    float* bmu = cnt + NN;                            //        128 f
    unsigned short* Wph = (unsigned short*)(bmu + OO);//     49,152 us
    unsigned short* Wpl = Wph + 3 * DD * OO;          //     49,152 us
    int* offsets = (int*)(Wpl + 3 * DD * OO);         //     50,004 i
    int* cursor  = offsets + 50004;                   //     50,000 i
    int* hist    = cursor + NN;                       //     50,000 i
    int* bsum    = hist + NN;                         //        256 i
    int* ebsum   = bsum + 256;                        //        256 i
    int2* ep     = (int2*)(ebsum + 256);              //    500,000 int2

    const int nscan = (NN + 255) / 256;               // 196

    hipMemsetAsync(hist, 0, NN * sizeof(int), stream);

    wfuse_k<<<3 * DD + 1, 128, 0, stream>>>(Wm, Wu, bm, Wph, Wpl, bmu);
    hist_k<<<(EE + 255) / 256, 256, 0, stream>>>(ei, hist);
    scan1_k<<<nscan, 256, 0, stream>>>(hist, bsum);
    scan2_k<<<1, 256, 0, stream>>>(bsum, ebsum, offsets, nscan);
    scan3_k<<<nscan, 256, 0, stream>>>(hist, ebsum, offsets, cursor);
    fill_k<<<(EE + 255) / 256, 256, 0, stream>>>(ei, cursor, ep);

    agg_k<<<(NN + 3) / 4, 256, 0, stream>>>(x, ea, offsets, ep, S, T, cnt);

    const int nblocks = (BN * NN + 63) / 64;
    gemm_k<<<nblocks, 256, 0, stream>>>(S, T, cnt, x, Wph, Wpl, bmu, bu, out);
}